// Round 14
// baseline (156.716 us; speedup 1.0000x reference)
//
#include <hip/hip_runtime.h>
#include <math.h>

// ---------------------------------------------------------------------------
// Types / helpers
// ---------------------------------------------------------------------------
typedef short bf16x8 __attribute__((ext_vector_type(8)));   // 8 bf16 (4 VGPRs)
typedef float f32x4  __attribute__((ext_vector_type(4)));

#define MFMA16 __builtin_amdgcn_mfma_f32_16x16x32_bf16
#define LOG2E 1.4426950408889634f

static __device__ __forceinline__ short f2bf(float f) {
  union { float f; unsigned u; } x; x.f = f;
  unsigned r = (x.u + 0x7FFFu + ((x.u >> 16) & 1u)) >> 16;  // RTNE
  return (short)r;
}
static __device__ __forceinline__ unsigned packbf(float a, float b) {
  return (unsigned)(unsigned short)f2bf(a) | ((unsigned)(unsigned short)f2bf(b) << 16);
}
static __device__ __forceinline__ float bf2f(short s) {
  union { unsigned u; float f; } x; x.u = ((unsigned)(unsigned short)s) << 16;
  return x.f;
}
static __device__ __forceinline__ void gload_lds16(const void* g, void* l) {
  __builtin_amdgcn_global_load_lds((const __attribute__((address_space(1))) void*)g,
                                   (__attribute__((address_space(3))) void*)l, 16, 0, 0);
}
static __device__ __forceinline__ float ex2(float x) {
  float r; asm("v_exp_f32 %0, %1" : "=v"(r) : "v"(x)); return r;
}
static __device__ __forceinline__ float rcpf(float x) {
  float r; asm("v_rcp_f32 %0, %1" : "=v"(r) : "v"(x)); return r;
}
static __device__ __forceinline__ unsigned cvtpk(float lo, float hi) {
  unsigned r; asm("v_cvt_pk_bf16_f32 %0, %1, %2" : "=v"(r) : "v"(lo), "v"(hi));
  return r;
}

// ---------------------------------------------------------------------------
// Transpose one 32x32 tile: fp32 in [K][N] -> bf16 out [N][K]
// ---------------------------------------------------------------------------
__device__ __forceinline__ void tr_tile(
    const float* __restrict__ in, short* __restrict__ out,
    int K, int N, int nt, int kt, float (*t)[33])
{
  int n0 = nt * 32, k0 = kt * 32;
  int tx = threadIdx.x & 31, ty = threadIdx.x >> 5;
  #pragma unroll
  for (int i = 0; i < 4; ++i)
    t[ty + 8 * i][tx] = in[(size_t)(k0 + ty + 8 * i) * N + n0 + tx];
  __syncthreads();
  #pragma unroll
  for (int i = 0; i < 4; ++i)
    out[(size_t)(n0 + ty + 8 * i) * K + k0 + tx] = f2bf(t[tx][ty + 8 * i]);
}

// Fused prep: weight transposes + x convert + RoPE cos/sin table. grid 14976.
__global__ __launch_bounds__(256) void prep_kernel(
    const float* __restrict__ x, const float* __restrict__ Wq,
    const float* __restrict__ Wk, const float* __restrict__ Wv,
    const float* __restrict__ WA, const float* __restrict__ WB,
    const float* __restrict__ Wo,
    short* __restrict__ xb, short* __restrict__ Wqt, short* __restrict__ Wkt,
    short* __restrict__ Wvt, short* __restrict__ WABt, short* __restrict__ Wot,
    float* __restrict__ RTab)
{
  __shared__ float t[32][33];
  int b = blockIdx.x;
  if (b < 4096)       tr_tile(Wq, Wqt, 2048, 2048, b & 63, b >> 6, t);
  else if (b < 5120)  { int c = b - 4096; tr_tile(Wk, Wkt, 2048, 512, c & 15, c >> 4, t); }
  else if (b < 6144)  { int c = b - 5120; tr_tile(Wv, Wvt, 2048, 512, c & 15, c >> 4, t); }
  else if (b < 6208)  { int c = b - 6144; tr_tile(WA, WABt, 2048, 32, 0, c, t); }
  else if (b < 6272)  { int c = b - 6208; tr_tile(WB, WABt + 32 * 2048, 2048, 32, 0, c, t); }
  else if (b < 10368) {
    int i = (b - 6272) * 256 + threadIdx.x;          // 4096 blocks, 1M float4
    float4 v = ((const float4*)x)[i];
    short4 o; o.x = f2bf(v.x); o.y = f2bf(v.y); o.z = f2bf(v.z); o.w = f2bf(v.w);
    ((short4*)xb)[i] = o;
  } else if (b < 14464) {
    int c = b - 10368;                               // 4096 blocks
    tr_tile(Wo, Wot, 2048, 2048, c & 63, c >> 6, t);
  } else {
    int i = (b - 14464) * 256 + threadIdx.x;         // 512 blocks, 131072 entries
    int d = i & 63, tt = i >> 6;
    float inv = __expf((float)d * -0.14391156831212789f);  // 10000^(-d/64)
    float ang = (float)tt * inv;
    float sn, cs;
    __sincosf(ang, &sn, &cs);
    RTab[(size_t)i * 2]     = cs;
    RTab[(size_t)i * 2 + 1] = sn;
  }
}

// RoPE on K only [2048][512] (4 heads, pairs (d, d+64)), table-driven. grid 2048.
__global__ __launch_bounds__(256) void ropek_kernel(short* __restrict__ K,
                                                    const float* __restrict__ RTab)
{
  int idx = blockIdx.x * 256 + threadIdx.x;   // < 2048*4*64
  int d  = idx & 63;
  int hh = (idx >> 6) & 3;
  int tt = idx >> 8;
  short* base = K + (size_t)tt * 512 + hh * 128 + d;
  float cs = RTab[((size_t)tt * 64 + d) * 2];
  float sn = RTab[((size_t)tt * 64 + d) * 2 + 1];
  float x1 = bf2f(base[0]), x2 = bf2f(base[64]);
  base[0]  = f2bf(x1 * cs - x2 * sn);
  base[64] = f2bf(x2 * cs + x1 * sn);
}

// ---------------------------------------------------------------------------
// bf16 MFMA GEMM core, C 128(M)x64(N) tile, BK=64, single-buffer LDS with
// full __syncthreads drains. Pre-swizzled-source idiom for the 128B-row
// bank conflict. (measured good r10-r13)
// ---------------------------------------------------------------------------
__device__ __forceinline__ void gemm12864_core(
    const short* __restrict__ A, const short* __restrict__ Bt,
    int m0, int n0, int Kd, short* Asm /*128x64*/, short* Bsm /*64x64*/,
    f32x4 acc[4][2])
{
  const int tid = threadIdx.x;
  const int lane = tid & 63, w = tid >> 6;
  const int lr = lane & 15, g4 = lane >> 4;
  const int wm = w >> 1, wn = w & 1;

  for (int k0 = 0; k0 < Kd; k0 += 64) {
    #pragma unroll
    for (int s = 0; s < 4; ++s) {
      int c = (s * 4 + w) * 64 + lane;          // 0..1023
      int row = c >> 3, q = c & 7;
      gload_lds16(A + (size_t)(m0 + row) * Kd + k0 + (q ^ (row & 7)) * 8,
                  Asm + c * 8);
    }
    #pragma unroll
    for (int s = 0; s < 2; ++s) {
      int c = (s * 4 + w) * 64 + lane;          // 0..511
      int row = c >> 3, q = c & 7;
      gload_lds16(Bt + (size_t)(n0 + row) * Kd + k0 + (q ^ (row & 7)) * 8,
                  Bsm + c * 8);
    }
    __syncthreads();
    #pragma unroll
    for (int kk = 0; kk < 2; ++kk) {
      bf16x8 af[4], bff[2];
      #pragma unroll
      for (int mi = 0; mi < 4; ++mi) {
        int row = wm * 64 + mi * 16 + lr;       // row&7 == lr&7
        af[mi] = *(const bf16x8*)(Asm + row * 64 +
                                  ((kk * 4 + g4) ^ (lr & 7)) * 8);
      }
      #pragma unroll
      for (int ni = 0; ni < 2; ++ni) {
        int row = wn * 32 + ni * 16 + lr;
        bff[ni] = *(const bf16x8*)(Bsm + row * 64 +
                                   ((kk * 4 + g4) ^ (lr & 7)) * 8);
      }
      #pragma unroll
      for (int mi = 0; mi < 4; ++mi)
        #pragma unroll
        for (int ni = 0; ni < 2; ++ni)
          acc[mi][ni] = MFMA16(af[mi], bff[ni], acc[mi][ni], 0, 0, 0);
    }
    __syncthreads();
  }
}

// Fused QKV + low-rank AB projection. grid 784 (1D, XCD-swizzled: 784=8x98).
__global__ __launch_bounds__(256, 3) void gemm_qkv_kernel(
    const short* __restrict__ xb, const short* __restrict__ Wqt,
    const short* __restrict__ Wkt, const short* __restrict__ Wvt,
    const short* __restrict__ WABt,
    short* __restrict__ Qb, short* __restrict__ Kb, short* __restrict__ Vtb,
    short* __restrict__ Ab, short* __restrict__ Bb)
{
  __shared__ __align__(16) short Asm[128 * 64];
  __shared__ __align__(16) short Bsm[64 * 64];
  f32x4 acc[4][2];
  #pragma unroll
  for (int i = 0; i < 4; ++i)
    #pragma unroll
    for (int j = 0; j < 2; ++j) acc[i][j] = (f32x4){0.f, 0.f, 0.f, 0.f};

  const int bid = (int)blockIdx.x;                 // 0..783
  const int swz = (bid & 7) * 98 + (bid >> 3);
  const int bx = swz % 49, by = swz / 49;

  const short* Bt; int mode, nl0;
  if (bx < 32)      { Bt = Wqt;  nl0 = bx * 64;        mode = 0; }
  else if (bx < 40) { Bt = Wkt;  nl0 = (bx - 32) * 64; mode = 1; }
  else if (bx < 48) { Bt = Wvt;  nl0 = (bx - 40) * 64; mode = 2; }
  else              { Bt = WABt; nl0 = 0;              mode = 3; }

  gemm12864_core(xb, Bt, by * 128, nl0, 2048, Asm, Bsm, acc);

  const int tid = threadIdx.x, lane = tid & 63, w = tid >> 6;
  const int lr = lane & 15, g4 = lane >> 4, wm = w >> 1, wn = w & 1;
  #pragma unroll
  for (int mi = 0; mi < 4; ++mi) {
    #pragma unroll
    for (int ni = 0; ni < 2; ++ni) {
      int mb = by * 128 + wm * 64 + mi * 16 + g4 * 4;
      int ncl = wn * 32 + ni * 16 + lr;    // 0..63 within tile
      int nc = nl0 + ncl;
      if (mode == 0) {
        #pragma unroll
        for (int r = 0; r < 4; ++r)
          Qb[(size_t)(mb + r) * 2048 + nc] = f2bf(acc[mi][ni][r]);
      } else if (mode == 1) {
        #pragma unroll
        for (int r = 0; r < 4; ++r)
          Kb[(size_t)(mb + r) * 512 + nc] = f2bf(acc[mi][ni][r]);
      } else if (mode == 2) {
        uint2 uu;
        uu.x = packbf(acc[mi][ni][0], acc[mi][ni][1]);
        uu.y = packbf(acc[mi][ni][2], acc[mi][ni][3]);
        *(uint2*)(Vtb + (size_t)nc * 2048 + mb) = uu;   // V^T [512][2048]
      } else {
        #pragma unroll
        for (int r = 0; r < 4; ++r) {
          float sv = acc[mi][ni][r];
          if (ncl < 32) Ab[(size_t)(mb + r) * 32 + ncl] = f2bf(sv * LOG2E);
          else          Bb[(size_t)(mb + r) * 32 + (ncl - 32)] = f2bf(sv);
        }
      }
    }
  }
}

// Output projection: out = AO(bf16) @ Wo -> fp32. grid 512 (1D, 512=8x64).
__global__ __launch_bounds__(256, 3) void gemm_out_kernel(
    const short* __restrict__ AO, const short* __restrict__ Wot,
    float* __restrict__ out)
{
  __shared__ __align__(16) short Asm[128 * 64];
  __shared__ __align__(16) short Bsm[64 * 64];
  f32x4 acc[4][2];
  #pragma unroll
  for (int i = 0; i < 4; ++i)
    #pragma unroll
    for (int j = 0; j < 2; ++j) acc[i][j] = (f32x4){0.f, 0.f, 0.f, 0.f};

  const int bid = (int)blockIdx.x;                 // 0..511
  const int swz = (bid & 7) * 64 + (bid >> 3);
  const int bx = swz % 32, by = swz / 32;

  gemm12864_core(AO, Wot, by * 128, bx * 64, 2048, Asm, Bsm, acc);

  const int tid = threadIdx.x, lane = tid & 63, w = tid >> 6;
  const int lr = lane & 15, g4 = lane >> 4, wm = w >> 1, wn = w & 1;
  #pragma unroll
  for (int mi = 0; mi < 4; ++mi)
    #pragma unroll
    for (int ni = 0; ni < 2; ++ni) {
      int mb = by * 128 + wm * 64 + mi * 16 + g4 * 4;
      int nc = bx * 64 + wn * 32 + ni * 16 + lr;
      #pragma unroll
      for (int r = 0; r < 4; ++r)
        out[(size_t)(mb + r) * 2048 + nc] = acc[mi][ni][r];
    }
}

// ---------------------------------------------------------------------------
// KV-split flash attention, 48KB LDS -> 3 blocks/CU. grid (16 heads, 48 y):
//   y<16 : qt=16+y, first half  tiles [0, c1)        -> partial buf 0
//   y<32 : qt=y,    second half tiles [c1, qt]       -> partial buf 1
//   y>=32: qt=47-y, full        tiles [0, qt]        -> AO direct
// where c1=(qt+2)/2. CU triples (y,y+16,y+32) sum to 33 tile-units.
// LDS: K0@0(16K) K1@16K(16K, Q overlay) Vs@32K(16K, A overlay).
// P overlays dead Kcur (after mid barrier). B in named-reg dbuf (r11 scheme).
// r7-verified barrier flow: top vmcnt(8/4)+bar -> QK -> softmax ->
// mid vmcnt(8/0)+bar -> P->Kcur -> PV -> end bar -> stage V[jt+1].
// ---------------------------------------------------------------------------
__global__ __launch_bounds__(256, 2) void attn_kernel(
    const short* __restrict__ Qg, const short* __restrict__ Kg,
    const short* __restrict__ Vtg, const short* __restrict__ Ag,
    const short* __restrict__ Bg, const float* __restrict__ pol_dir,
    const float* __restrict__ pol_gate, const float* __restrict__ gtp_gamma,
    const float* __restrict__ RTab, short* __restrict__ AO,
    short* __restrict__ Opart, float* __restrict__ MLp)
{
  __shared__ __align__(16) char lds[49152];
  char* const K0s = lds;
  char* const K1s = lds + 16384;
  char* const Vs  = lds + 32768;

  const int tid = threadIdx.x;
  const int lane = tid & 63, w = tid >> 6;
  const int lr = lane & 15, g4 = lane >> 4;
  const int h  = blockIdx.x;
  const int y  = blockIdx.y;
  int qt, jlo, jhi, half;
  if (y < 16)      { qt = 16 + y; int c1 = (qt + 2) >> 1; jlo = 0;  jhi = c1 - 1; half = 0; }
  else if (y < 32) { qt = y;      int c1 = (qt + 2) >> 1; jlo = c1; jhi = qt;     half = 1; }
  else             { qt = 47 - y; jlo = 0; jhi = qt; half = -1; }
  const int q0 = qt * 64;
  const int kvh = h >> 2;
  const short* Kh = Kg + kvh * 128;
  const short* Vh = Vtg + (size_t)(kvh * 128) * 2048;

  float pol   = fminf(fmaxf(pol_dir[h], -1.f), 1.f);
  float gamma = fmaxf(log1pf(__expf(gtp_gamma[h])), 1e-6f);
  float gate  = (1.f / (1.f + __expf(-pol_gate[h]))) * LOG2E;
  const float c_h  = -(pol * (1.f / 4096.f) + gamma) * LOG2E;  // log2-domain
  const float c16  = 16.f * c_h;
  const float chr1 = c_h, chr2 = c_h + c_h, chr3 = chr2 + c_h;
  const float sc = 0.08838834764831845f * LOG2E;   // log2e/sqrt(128)
  const f32x4 z4 = {0.f, 0.f, 0.f, 0.f};

  // ---- prologue: issue K[jlo]->K0 (4), B[jlo]->regs (4) ----
  #pragma unroll
  for (int s = 0; s < 4; ++s) {
    int idx = (w * 4 + s) * 64 + lane;
    int row = idx >> 4, slot = idx & 15;
    gload_lds16(Kh + (size_t)(jlo * 64 + row) * 512 + (slot ^ (row & 7)) * 8,
                K0s + (w * 4 + s) * 1024);
  }
  bf16x8 bA0, bA1, bA2, bA3, bB0, bB1, bB2, bB3;
  bA0 = *(const bf16x8*)(Bg + (size_t)(jlo * 64 + 0 * 16 + lr) * 32 + g4 * 8);
  bA1 = *(const bf16x8*)(Bg + (size_t)(jlo * 64 + 1 * 16 + lr) * 32 + g4 * 8);
  bA2 = *(const bf16x8*)(Bg + (size_t)(jlo * 64 + 2 * 16 + lr) * 32 + g4 * 8);
  bA3 = *(const bf16x8*)(Bg + (size_t)(jlo * 64 + 3 * 16 + lr) * 32 + g4 * 8);

  // ---- Q -> K1 overlay (swizzled, table RoPE), A -> Vs overlay ----
  #pragma unroll
  for (int s = 0; s < 2; ++s) {
    int c = tid + s * 256;            // 0..511
    int row = c >> 3, sl = c & 7;
    const short* qrow = Qg + (size_t)(q0 + row) * 2048 + h * 128;
    int4 vlo = *(const int4*)(qrow + sl * 8);
    int4 vhi = *(const int4*)(qrow + 64 + sl * 8);
    const float* tabrow = RTab + (size_t)(q0 + row) * 128 + sl * 16;
    float tab[16];
    *(float4*)(tab + 0)  = *(const float4*)(tabrow + 0);
    *(float4*)(tab + 4)  = *(const float4*)(tabrow + 4);
    *(float4*)(tab + 8)  = *(const float4*)(tabrow + 8);
    *(float4*)(tab + 12) = *(const float4*)(tabrow + 12);
    short* lop = (short*)&vlo;
    short* hip = (short*)&vhi;
    short rlo[8], rhi[8];
    #pragma unroll
    for (int j = 0; j < 8; ++j) {
      float cs = tab[2 * j], sn = tab[2 * j + 1];
      float x1 = bf2f(lop[j]), x2 = bf2f(hip[j]);
      rlo[j] = f2bf(x1 * cs - x2 * sn);
      rhi[j] = f2bf(x2 * cs + x1 * sn);
    }
    *(int4*)(K1s + row * 256 + ((sl * 16) ^ ((row & 7) << 4))) = *(int4*)rlo;
    *(int4*)(K1s + row * 256 + (((sl + 8) * 16) ^ ((row & 7) << 4))) = *(int4*)rhi;
  }
  {
    int row = tid >> 2, sl = tid & 3;
    int4 va = *(const int4*)(Ag + (size_t)(q0 + row) * 32 + sl * 8);
    *(int4*)(Vs + row * 80 + sl * 16) = va;
  }
  asm volatile("s_waitcnt lgkmcnt(0)" ::: "memory");
  __builtin_amdgcn_s_barrier();

  // hoist Q frags (q-row = w*16+lr) and A frag
  bf16x8 qf[4];
  #pragma unroll
  for (int kk = 0; kk < 4; ++kk)
    qf[kk] = *(const bf16x8*)(K1s + (w * 16 + lr) * 256 +
                              ((kk * 64 + g4 * 16) ^ ((lr & 7) << 4)));
  bf16x8 afr = *(const bf16x8*)(Vs + (w * 16 + lr) * 80 + g4 * 16);
  asm volatile("s_waitcnt lgkmcnt(0)" ::: "memory");
  __builtin_amdgcn_s_barrier();   // K1/Vs overlays dead

  // ---- issue V[jlo] -> Vs (4) ----
  #pragma unroll
  for (int s = 0; s < 4; ++s) {
    int idx = (w * 4 + s) * 64 + lane;
    int row = idx >> 3, slot = idx & 7;
    gload_lds16(Vh + (size_t)row * 2048 + jlo * 64 + (slot ^ (row & 7)) * 8,
                Vs + (w * 4 + s) * 1024);
  }

  f32x4 acc_o[8];
  #pragma unroll
  for (int i = 0; i < 8; ++i) acc_o[i] = z4;
  float m_st = -INFINITY, l_st = 0.f;

#define ATTN_TILE(JT, KC, KN, BC0, BC1, BC2, BC3, BN0, BN1, BN2, BN3)         \
  do {                                                                        \
    const int j0 = (JT) * 64;                                                 \
    const bool pf = (JT) < jhi;                                               \
    if (pf) {                                                                 \
      _Pragma("unroll")                                                       \
      for (int s = 0; s < 4; ++s) {                                           \
        int idx = (w * 4 + s) * 64 + lane;                                    \
        int row = idx >> 4, slot = idx & 15;                                  \
        gload_lds16(Kh + (size_t)(j0 + 64 + row) * 512 + (slot ^ (row & 7)) * 8, \
                    (KN) + (w * 4 + s) * 1024);                               \
      }                                                                       \
      asm volatile("s_waitcnt vmcnt(8)" ::: "memory");                        \
    } else {                                                                  \
      asm volatile("s_waitcnt vmcnt(4)" ::: "memory");                        \
    }                                                                         \
    __builtin_amdgcn_s_barrier();  /* K[JT] visible; B landed */              \
    f32x4 acc_s[4], md4[4];                                                   \
    __builtin_amdgcn_s_setprio(1);                                            \
    _Pragma("unroll")                                                         \
    for (int cb = 0; cb < 4; ++cb) {                                          \
      acc_s[cb] = z4;                                                         \
      _Pragma("unroll")                                                       \
      for (int kk = 0; kk < 4; ++kk) {                                        \
        bf16x8 kf = *(const bf16x8*)((KC) + (cb * 16 + lr) * 256 +            \
                                     ((kk * 64 + g4 * 16) ^ ((lr & 7) << 4)));\
        acc_s[cb] = MFMA16(kf, qf[kk], acc_s[cb], 0, 0, 0);                   \
      }                                                                       \
    }                                                                         \
    md4[0] = MFMA16(BC0, afr, z4, 0, 0, 0);                                   \
    md4[1] = MFMA16(BC1, afr, z4, 0, 0, 0);                                   \
    md4[2] = MFMA16(BC2, afr, z4, 0, 0, 0);                                   \
    md4[3] = MFMA16(BC3, afr, z4, 0, 0, 0);                                   \
    __builtin_amdgcn_s_setprio(0);                                            \
    if (pf) {                                                                 \
      BN0 = *(const bf16x8*)(Bg + (size_t)(j0 + 64 + 0 * 16 + lr) * 32 + g4 * 8); \
      BN1 = *(const bf16x8*)(Bg + (size_t)(j0 + 64 + 1 * 16 + lr) * 32 + g4 * 8); \
      BN2 = *(const bf16x8*)(Bg + (size_t)(j0 + 64 + 2 * 16 + lr) * 32 + g4 * 8); \
      BN3 = *(const bf16x8*)(Bg + (size_t)(j0 + 64 + 3 * 16 + lr) * 32 + g4 * 8); \
    }                                                                         \
    const int dq = q0 + w * 16 + lr - j0;                                     \
    float bq = c_h * (float)(dq - g4 * 4);                                    \
    _Pragma("unroll")                                                         \
    for (int cb = 0; cb < 4; ++cb) {                                          \
      float bcb = bq - c16 * (float)cb;                                       \
      float sig0 = rcpf(1.f + ex2(-md4[cb][0]));                              \
      float sig1 = rcpf(1.f + ex2(-md4[cb][1]));                              \
      float sig2 = rcpf(1.f + ex2(-md4[cb][2]));                              \
      float sig3 = rcpf(1.f + ex2(-md4[cb][3]));                              \
      acc_s[cb][0] = fmaf(acc_s[cb][0], sc, fmaf(gate, sig0, bcb));           \
      acc_s[cb][1] = fmaf(acc_s[cb][1], sc, fmaf(gate, sig1, bcb - chr1));    \
      acc_s[cb][2] = fmaf(acc_s[cb][2], sc, fmaf(gate, sig2, bcb - chr2));    \
      acc_s[cb][3] = fmaf(acc_s[cb][3], sc, fmaf(gate, sig3, bcb - chr3));    \
    }                                                                         \
    if ((JT) == qt) {                                                         \
      _Pragma("unroll")                                                       \
      for (int cb = 0; cb < 4; ++cb)                                          \
        _Pragma("unroll")                                                     \
        for (int r = 0; r < 4; ++r)                                           \
          if (cb * 16 + g4 * 4 + r > dq) acc_s[cb][r] = -INFINITY;            \
    }                                                                         \
    float t0 = fmaxf(fmaxf(acc_s[0][0], acc_s[0][1]), acc_s[0][2]);           \
    float t1 = fmaxf(fmaxf(acc_s[0][3], acc_s[1][0]), acc_s[1][1]);           \
    float t2 = fmaxf(fmaxf(acc_s[1][2], acc_s[1][3]), acc_s[2][0]);           \
    float t3 = fmaxf(fmaxf(acc_s[2][1], acc_s[2][2]), acc_s[2][3]);           \
    float t4 = fmaxf(fmaxf(acc_s[3][0], acc_s[3][1]), acc_s[3][2]);           \
    float mx = fmaxf(fmaxf(fmaxf(t0, t1), t2),                                \
                     fmaxf(fmaxf(t3, t4), acc_s[3][3]));                      \
    mx = fmaxf(mx, __shfl_xor(mx, 16));                                       \
    mx = fmaxf(mx, __shfl_xor(mx, 32));                                       \
    if (!__all(mx - m_st <= 11.5415603f)) {                                   \
      float mn = fmaxf(m_st, mx);                                             \
      float es = ex2(m_st - mn);                                              \
      l_st *= es;                                                             \
      m_st = mn;                                                              \
      float es4[4];                                                           \
      _Pragma("unroll")                                                       \
      for (int r = 0; r < 4; ++r) es4[r] = __shfl(es, g4 * 4 + r, 64);        \
      _Pragma("unroll")                                                       \
      for (int db = 0; db < 8; ++db)                                          \
        _Pragma("unroll")                                                     \
        for (int r = 0; r < 4; ++r) acc_o[db][r] *= es4[r];                   \
    }                                                                         \
    float rs = 0.f;                                                           \
    _Pragma("unroll")                                                         \
    for (int cb = 0; cb < 4; ++cb)                                            \
      _Pragma("unroll")                                                       \
      for (int r = 0; r < 4; ++r) {                                           \
        float p = ex2(acc_s[cb][r] - m_st);                                   \
        acc_s[cb][r] = p;                                                     \
        rs += p;                                                              \
      }                                                                       \
    rs += __shfl_xor(rs, 16);                                                 \
    rs += __shfl_xor(rs, 32);                                                 \
    l_st += rs;                                                               \
    if (pf) asm volatile("s_waitcnt vmcnt(8)" ::: "memory");                  \
    else    asm volatile("s_waitcnt vmcnt(0)" ::: "memory");                  \
    __builtin_amdgcn_s_barrier();  /* all QK reads done; V visible */         \
    char* Pw = (KC) + w * 2048;                                               \
    _Pragma("unroll")                                                         \
    for (int cb = 0; cb < 4; ++cb) {                                          \
      uint2 uu;                                                               \
      uu.x = cvtpk(acc_s[cb][0], acc_s[cb][1]);                               \
      uu.y = cvtpk(acc_s[cb][2], acc_s[cb][3]);                               \
      *(uint2*)(Pw + lr * 128 + ((cb * 32 + g4 * 8) ^ ((lr & 7) << 4))) = uu; \
    }                                                                         \
    asm volatile("s_waitcnt lgkmcnt(0)" ::: "memory");                        \
    __builtin_amdgcn_sched_barrier(0);                                        \
    __builtin_amdgcn_s_setprio(1);                                            \
    _Pragma("unroll")                                                         \
    for (int kk = 0; kk < 2; ++kk) {                                          \
      bf16x8 pfr = *(const bf16x8*)(Pw + lr * 128 +                           \
                                    ((kk * 64 + g4 * 16) ^ ((lr & 7) << 4))); \
      _Pragma("unroll")                                                       \
      for (int db = 0; db < 8; ++db) {                                        \
        bf16x8 vf = *(const bf16x8*)(Vs + (db * 16 + lr) * 128 +              \
                                     ((kk * 64 + g4 * 16) ^ ((lr & 7) << 4)));\
        acc_o[db] = MFMA16(pfr, vf, acc_o[db], 0, 0, 0);                      \
      }                                                                       \
    }                                                                         \
    __builtin_amdgcn_s_setprio(0);                                            \
    asm volatile("s_waitcnt lgkmcnt(0)" ::: "memory");                        \
    __builtin_amdgcn_sched_barrier(0);                                        \
    __builtin_amdgcn_s_barrier();  /* P/V reads done */                       \
    if (pf) {                                                                 \
      _Pragma("unroll")                                                       \
      for (int s = 0; s < 4; ++s) {                                           \
        int idx = (w * 4 + s) * 64 + lane;                                    \
        int row = idx >> 3, slot = idx & 7;                                   \
        gload_lds16(Vh + (size_t)row * 2048 + (j0 + 64) + (slot ^ (row & 7)) * 8, \
                    Vs + (w * 4 + s) * 1024);                                 \
      }                                                                       \
    }                                                                         \
  } while (0)

  for (int jt = jlo; jt <= jhi; jt += 2) {
    ATTN_TILE(jt, K0s, K1s, bA0, bA1, bA2, bA3, bB0, bB1, bB2, bB3);
    if (jt + 1 <= jhi)
      ATTN_TILE(jt + 1, K1s, K0s, bB0, bB1, bB2, bB3, bA0, bA1, bA2, bA3);
  }
#undef ATTN_TILE

  if (half < 0) {
    // single: normalize, store bf16 AO
    float lrcp[4];
    #pragma unroll
    for (int r = 0; r < 4; ++r) lrcp[r] = 1.f / __shfl(l_st, g4 * 4 + r, 64);
    #pragma unroll
    for (int db = 0; db < 8; ++db)
      #pragma unroll
      for (int r = 0; r < 4; ++r)
        AO[(size_t)(q0 + w * 16 + g4 * 4 + r) * 2048 + h * 128 + db * 16 + lr] =
            f2bf(acc_o[db][r] * lrcp[r]);
  } else {
    // partial: unnormalized bf16 O + per-row (m, l)
    short* Op = Opart + ((size_t)half * 16 + h) * (1024 * 128);
    int rowb = q0 - 1024 + w * 16;
    #pragma unroll
    for (int db = 0; db < 8; ++db)
      #pragma unroll
      for (int r = 0; r < 4; ++r)
        Op[(size_t)(rowb + g4 * 4 + r) * 128 + db * 16 + lr] = f2bf(acc_o[db][r]);
    if (g4 == 0) {
      size_t mi = (((size_t)half * 16 + h) * 1024 + (size_t)(rowb + lr)) * 2;
      MLp[mi]     = m_st;
      MLp[mi + 1] = l_st;
    }
  }
}

// ---------------------------------------------------------------------------
// Combine the two KV-split halves for rows 1024..2047. grid 1024 x 256.
// ---------------------------------------------------------------------------
__global__ __launch_bounds__(256) void combine_kernel(
    const short* __restrict__ Opart, const float* __restrict__ MLp,
    short* __restrict__ AO)
{
  int idx = blockIdx.x * 256 + threadIdx.x;   // 0..262143
  int ch = idx & 15;
  int rl = (idx >> 4) & 1023;
  int h  = idx >> 14;
  size_t r0 = ((size_t)h * 1024 + rl) * 2;
  float m0 = MLp[r0],               l0 = MLp[r0 + 1];
  float m1 = MLp[16 * 1024 * 2 + r0], l1 = MLp[16 * 1024 * 2 + r0 + 1];
  float M  = fmaxf(m0, m1);
  float w0 = ex2(m0 - M), w1 = ex2(m1 - M);
  float rden = rcpf(fmaf(l0, w0, l1 * w1));
  float f0 = w0 * rden, f1 = w1 * rden;
  const short* O0 = Opart + (size_t)h * (1024 * 128) + (size_t)rl * 128 + ch * 8;
  const short* O1 = O0 + (size_t)16 * 1024 * 128;
  int4 a = *(const int4*)O0;
  int4 b = *(const int4*)O1;
  const short* ap = (const short*)&a;
  const short* bp = (const short*)&b;
  short o[8];
  #pragma unroll
  for (int j = 0; j < 8; ++j)
    o[j] = f2bf(bf2f(ap[j]) * f0 + bf2f(bp[j]) * f1);
  *(int4*)(AO + (size_t)(1024 + rl) * 2048 + h * 128 + ch * 8) = *(int4*)o;
}

// ---------------------------------------------------------------------------
// Launch
// ---------------------------------------------------------------------------
extern "C" void kernel_launch(void* const* d_in, const int* in_sizes, int n_in,
                              void* d_out, int out_size, void* d_ws, size_t ws_size,
                              hipStream_t stream) {
  const float* x         = (const float*)d_in[0];
  const float* Wq        = (const float*)d_in[1];
  const float* Wk        = (const float*)d_in[2];
  const float* Wv        = (const float*)d_in[3];
  const float* Wo        = (const float*)d_in[4];
  const float* pol_dir   = (const float*)d_in[5];
  const float* pol_WA    = (const float*)d_in[6];
  const float* pol_WB    = (const float*)d_in[7];
  const float* pol_gate  = (const float*)d_in[8];
  const float* gtp_gamma = (const float*)d_in[9];
  float* out = (float*)d_out;

  char* ws = (char*)d_ws;
  short* Qb   = (short*)(ws);                    // 2048x2048 bf16 = 8 MB
  short* Kb   = (short*)(ws + 8388608);          // 2048x512  bf16 = 2 MB
  short* Vtb  = (short*)(ws + 10485760);         // 512x2048  bf16 = 2 MB (V^T)
  short* Ab   = (short*)(ws + 12582912);         // 2048x32   bf16 = 128 KB
  short* Bb   = (short*)(ws + 12713984);         // 2048x32   bf16 = 128 KB
  short* Wot  = (short*)(ws + 12845056);         // 8 MB
  short* Wqt  = (short*)(ws + 21233664);         // 8 MB (reused as AO after qkv)
  short* AO   = Wqt;                             // written by attn/combine
  short* Wkt  = (short*)(ws + 29622272);         // 2 MB
  short* Wvt  = (short*)(ws + 31719424);         // 2 MB
  short* WABt = (short*)(ws + 33816576);         // 512 KB
  short* xb   = (short*)(ws + 34340864);         // 8 MB (reused as Opart after qkv)
  short* Opart = xb;                             // 2x16x1024x128 bf16 = 8 MB
  float* RTab = (float*)(ws + 42729472);         // 1 MB
  float* MLp  = (float*)(ws + 43778048);         // 2x16x1024x2 f32 = 256 KB
  // total ~44 MB

  prep_kernel<<<14976, 256, 0, stream>>>(x, Wq, Wk, Wv, pol_WA, pol_WB, Wo,
                                         xb, Wqt, Wkt, Wvt, WABt, Wot, RTab);
  gemm_qkv_kernel<<<784, 256, 0, stream>>>(xb, Wqt, Wkt, Wvt, WABt,
                                           Qb, Kb, Vtb, Ab, Bb);
  ropek_kernel<<<2048, 256, 0, stream>>>(Kb, RTab);
  attn_kernel<<<dim3(16, 48), 256, 0, stream>>>(Qb, Kb, Vtb, Ab, Bb,
                                                pol_dir, pol_gate, gtp_gamma,
                                                RTab, AO, Opart, MLp);
  combine_kernel<<<1024, 256, 0, stream>>>(Opart, MLp, AO);
  gemm_out_kernel<<<512, 256, 0, stream>>>(AO, Wot, out);
}

// Round 15
// 150.546 us; speedup vs baseline: 1.0410x; 1.0410x over previous
//
#include <hip/hip_runtime.h>
#include <math.h>

// ---------------------------------------------------------------------------
// Types / helpers
// ---------------------------------------------------------------------------
typedef short bf16x8 __attribute__((ext_vector_type(8)));   // 8 bf16 (4 VGPRs)
typedef float f32x4  __attribute__((ext_vector_type(4)));

#define MFMA16 __builtin_amdgcn_mfma_f32_16x16x32_bf16
#define LOG2E 1.4426950408889634f

static __device__ __forceinline__ short f2bf(float f) {
  union { float f; unsigned u; } x; x.f = f;
  unsigned r = (x.u + 0x7FFFu + ((x.u >> 16) & 1u)) >> 16;  // RTNE
  return (short)r;
}
static __device__ __forceinline__ unsigned packbf(float a, float b) {
  return (unsigned)(unsigned short)f2bf(a) | ((unsigned)(unsigned short)f2bf(b) << 16);
}
static __device__ __forceinline__ float bf2f(short s) {
  union { unsigned u; float f; } x; x.u = ((unsigned)(unsigned short)s) << 16;
  return x.f;
}
static __device__ __forceinline__ void gload_lds16(const void* g, void* l) {
  __builtin_amdgcn_global_load_lds((const __attribute__((address_space(1))) void*)g,
                                   (__attribute__((address_space(3))) void*)l, 16, 0, 0);
}
static __device__ __forceinline__ float ex2(float x) {
  float r; asm("v_exp_f32 %0, %1" : "=v"(r) : "v"(x)); return r;
}
static __device__ __forceinline__ float rcpf(float x) {
  float r; asm("v_rcp_f32 %0, %1" : "=v"(r) : "v"(x)); return r;
}
static __device__ __forceinline__ unsigned cvtpk(float lo, float hi) {
  unsigned r; asm("v_cvt_pk_bf16_f32 %0, %1, %2" : "=v"(r) : "v"(lo), "v"(hi));
  return r;
}

// ---------------------------------------------------------------------------
// Transpose one 32x32 tile: fp32 in [K][N] -> bf16 out [N][K]
// ---------------------------------------------------------------------------
__device__ __forceinline__ void tr_tile(
    const float* __restrict__ in, short* __restrict__ out,
    int K, int N, int nt, int kt, float (*t)[33])
{
  int n0 = nt * 32, k0 = kt * 32;
  int tx = threadIdx.x & 31, ty = threadIdx.x >> 5;
  #pragma unroll
  for (int i = 0; i < 4; ++i)
    t[ty + 8 * i][tx] = in[(size_t)(k0 + ty + 8 * i) * N + n0 + tx];
  __syncthreads();
  #pragma unroll
  for (int i = 0; i < 4; ++i)
    out[(size_t)(n0 + ty + 8 * i) * K + k0 + tx] = f2bf(t[tx][ty + 8 * i]);
}

// Fused prep: Wq/Wk/Wv/WA/WB/Wo transposes + x fp32->bf16 convert. grid 14464.
__global__ __launch_bounds__(256) void prep_kernel(
    const float* __restrict__ x, const float* __restrict__ Wq,
    const float* __restrict__ Wk, const float* __restrict__ Wv,
    const float* __restrict__ WA, const float* __restrict__ WB,
    const float* __restrict__ Wo,
    short* __restrict__ xb, short* __restrict__ Wqt, short* __restrict__ Wkt,
    short* __restrict__ Wvt, short* __restrict__ WABt, short* __restrict__ Wot)
{
  __shared__ float t[32][33];
  int b = blockIdx.x;
  if (b < 4096)       tr_tile(Wq, Wqt, 2048, 2048, b & 63, b >> 6, t);
  else if (b < 5120)  { int c = b - 4096; tr_tile(Wk, Wkt, 2048, 512, c & 15, c >> 4, t); }
  else if (b < 6144)  { int c = b - 5120; tr_tile(Wv, Wvt, 2048, 512, c & 15, c >> 4, t); }
  else if (b < 6208)  { int c = b - 6144; tr_tile(WA, WABt, 2048, 32, 0, c, t); }
  else if (b < 6272)  { int c = b - 6208; tr_tile(WB, WABt + 32 * 2048, 2048, 32, 0, c, t); }
  else if (b < 10368) {
    int i = (b - 6272) * 256 + threadIdx.x;          // 4096 blocks, 1M float4
    float4 v = ((const float4*)x)[i];
    short4 o; o.x = f2bf(v.x); o.y = f2bf(v.y); o.z = f2bf(v.z); o.w = f2bf(v.w);
    ((short4*)xb)[i] = o;
  } else {
    int c = b - 10368;                               // 4096 blocks
    tr_tile(Wo, Wot, 2048, 2048, c & 63, c >> 6, t);
  }
}

// RoPE on K only [2048][512] (4 heads, pairs (d, d+64)). grid 2048.
__global__ __launch_bounds__(256) void ropek_kernel(short* __restrict__ K)
{
  int idx = blockIdx.x * 256 + threadIdx.x;   // < 2048*4*64
  int d  = idx & 63;
  int hh = (idx >> 6) & 3;
  int tt = idx >> 8;
  short* base = K + (size_t)tt * 512 + hh * 128 + d;
  float inv = __expf((float)d * -0.14391156831212789f);  // 10000^(-d/64)
  float ang = (float)tt * inv;
  float sn, cs;
  __sincosf(ang, &sn, &cs);
  float x1 = bf2f(base[0]), x2 = bf2f(base[64]);
  base[0]  = f2bf(x1 * cs - x2 * sn);
  base[64] = f2bf(x2 * cs + x1 * sn);
}

// ---------------------------------------------------------------------------
// bf16 MFMA GEMM core, C 128(M)x64(N) tile, BK=64, single-buffer LDS with
// full __syncthreads drains. Pre-swizzled-source idiom for the 128B-row
// bank conflict. (measured good r10-r13)
// ---------------------------------------------------------------------------
__device__ __forceinline__ void gemm12864_core(
    const short* __restrict__ A, const short* __restrict__ Bt,
    int m0, int n0, int Kd, short* Asm /*128x64*/, short* Bsm /*64x64*/,
    f32x4 acc[4][2])
{
  const int tid = threadIdx.x;
  const int lane = tid & 63, w = tid >> 6;
  const int lr = lane & 15, g4 = lane >> 4;
  const int wm = w >> 1, wn = w & 1;

  for (int k0 = 0; k0 < Kd; k0 += 64) {
    #pragma unroll
    for (int s = 0; s < 4; ++s) {
      int c = (s * 4 + w) * 64 + lane;          // 0..1023
      int row = c >> 3, q = c & 7;
      gload_lds16(A + (size_t)(m0 + row) * Kd + k0 + (q ^ (row & 7)) * 8,
                  Asm + c * 8);
    }
    #pragma unroll
    for (int s = 0; s < 2; ++s) {
      int c = (s * 4 + w) * 64 + lane;          // 0..511
      int row = c >> 3, q = c & 7;
      gload_lds16(Bt + (size_t)(n0 + row) * Kd + k0 + (q ^ (row & 7)) * 8,
                  Bsm + c * 8);
    }
    __syncthreads();
    #pragma unroll
    for (int kk = 0; kk < 2; ++kk) {
      bf16x8 af[4], bff[2];
      #pragma unroll
      for (int mi = 0; mi < 4; ++mi) {
        int row = wm * 64 + mi * 16 + lr;       // row&7 == lr&7
        af[mi] = *(const bf16x8*)(Asm + row * 64 +
                                  ((kk * 4 + g4) ^ (lr & 7)) * 8);
      }
      #pragma unroll
      for (int ni = 0; ni < 2; ++ni) {
        int row = wn * 32 + ni * 16 + lr;
        bff[ni] = *(const bf16x8*)(Bsm + row * 64 +
                                   ((kk * 4 + g4) ^ (lr & 7)) * 8);
      }
      #pragma unroll
      for (int mi = 0; mi < 4; ++mi)
        #pragma unroll
        for (int ni = 0; ni < 2; ++ni)
          acc[mi][ni] = MFMA16(af[mi], bff[ni], acc[mi][ni], 0, 0, 0);
    }
    __syncthreads();
  }
}

// Fused QKV + low-rank AB projection. grid 784 (1D, XCD-swizzled: 784=8x98).
__global__ __launch_bounds__(256, 3) void gemm_qkv_kernel(
    const short* __restrict__ xb, const short* __restrict__ Wqt,
    const short* __restrict__ Wkt, const short* __restrict__ Wvt,
    const short* __restrict__ WABt,
    short* __restrict__ Qb, short* __restrict__ Kb, short* __restrict__ Vtb,
    short* __restrict__ Ab, short* __restrict__ Bb)
{
  __shared__ __align__(16) short Asm[128 * 64];
  __shared__ __align__(16) short Bsm[64 * 64];
  f32x4 acc[4][2];
  #pragma unroll
  for (int i = 0; i < 4; ++i)
    #pragma unroll
    for (int j = 0; j < 2; ++j) acc[i][j] = (f32x4){0.f, 0.f, 0.f, 0.f};

  const int bid = (int)blockIdx.x;                 // 0..783
  const int swz = (bid & 7) * 98 + (bid >> 3);
  const int bx = swz % 49, by = swz / 49;

  const short* Bt; int mode, nl0;
  if (bx < 32)      { Bt = Wqt;  nl0 = bx * 64;        mode = 0; }
  else if (bx < 40) { Bt = Wkt;  nl0 = (bx - 32) * 64; mode = 1; }
  else if (bx < 48) { Bt = Wvt;  nl0 = (bx - 40) * 64; mode = 2; }
  else              { Bt = WABt; nl0 = 0;              mode = 3; }

  gemm12864_core(xb, Bt, by * 128, nl0, 2048, Asm, Bsm, acc);

  const int tid = threadIdx.x, lane = tid & 63, w = tid >> 6;
  const int lr = lane & 15, g4 = lane >> 4, wm = w >> 1, wn = w & 1;
  #pragma unroll
  for (int mi = 0; mi < 4; ++mi) {
    #pragma unroll
    for (int ni = 0; ni < 2; ++ni) {
      int mb = by * 128 + wm * 64 + mi * 16 + g4 * 4;
      int ncl = wn * 32 + ni * 16 + lr;    // 0..63 within tile
      int nc = nl0 + ncl;
      if (mode == 0) {
        #pragma unroll
        for (int r = 0; r < 4; ++r)
          Qb[(size_t)(mb + r) * 2048 + nc] = f2bf(acc[mi][ni][r]);
      } else if (mode == 1) {
        #pragma unroll
        for (int r = 0; r < 4; ++r)
          Kb[(size_t)(mb + r) * 512 + nc] = f2bf(acc[mi][ni][r]);
      } else if (mode == 2) {
        uint2 uu;
        uu.x = packbf(acc[mi][ni][0], acc[mi][ni][1]);
        uu.y = packbf(acc[mi][ni][2], acc[mi][ni][3]);
        *(uint2*)(Vtb + (size_t)nc * 2048 + mb) = uu;   // V^T [512][2048]
      } else {
        #pragma unroll
        for (int r = 0; r < 4; ++r) {
          float sv = acc[mi][ni][r];
          if (ncl < 32) Ab[(size_t)(mb + r) * 32 + ncl] = f2bf(sv * LOG2E);
          else          Bb[(size_t)(mb + r) * 32 + (ncl - 32)] = f2bf(sv);
        }
      }
    }
  }
}

// Output projection: out = AO(bf16) @ Wo -> fp32. grid 512 (1D, 512=8x64).
__global__ __launch_bounds__(256, 3) void gemm_out_kernel(
    const short* __restrict__ AO, const short* __restrict__ Wot,
    float* __restrict__ out)
{
  __shared__ __align__(16) short Asm[128 * 64];
  __shared__ __align__(16) short Bsm[64 * 64];
  f32x4 acc[4][2];
  #pragma unroll
  for (int i = 0; i < 4; ++i)
    #pragma unroll
    for (int j = 0; j < 2; ++j) acc[i][j] = (f32x4){0.f, 0.f, 0.f, 0.f};

  const int bid = (int)blockIdx.x;                 // 0..511
  const int swz = (bid & 7) * 64 + (bid >> 3);
  const int bx = swz % 32, by = swz / 32;

  gemm12864_core(AO, Wot, by * 128, bx * 64, 2048, Asm, Bsm, acc);

  const int tid = threadIdx.x, lane = tid & 63, w = tid >> 6;
  const int lr = lane & 15, g4 = lane >> 4, wm = w >> 1, wn = w & 1;
  #pragma unroll
  for (int mi = 0; mi < 4; ++mi)
    #pragma unroll
    for (int ni = 0; ni < 2; ++ni) {
      int mb = by * 128 + wm * 64 + mi * 16 + g4 * 4;
      int nc = bx * 64 + wn * 32 + ni * 16 + lr;
      #pragma unroll
      for (int r = 0; r < 4; ++r)
        out[(size_t)(mb + r) * 2048 + nc] = acc[mi][ni][r];
    }
}

// ---------------------------------------------------------------------------
// Flash attention — r6 structure (measured 74.6us x3) with Q-RoPE fused into
// the Q-staging prologue. bf16 MFMA, exp2-domain softmax.
// grid (16 heads, 32 y), qt = (y<16) ? 31-y : y-16 (balanced pairing).
// LDS-double-buffered K (global_load_lds, pre-swizzled source), single V
// staged after the end barrier (counted vmcnt before PV). LDS 66KB.
// ---------------------------------------------------------------------------
__global__ __launch_bounds__(256, 2) void attn_kernel(
    const short* __restrict__ Qg, const short* __restrict__ Kg,
    const short* __restrict__ Vtg, const short* __restrict__ Ag,
    const short* __restrict__ Bg, const float* __restrict__ pol_dir,
    const float* __restrict__ pol_gate, const float* __restrict__ gtp_gamma,
    short* __restrict__ AO)
{
  // layout: Kb0 @0 (16K), Kb1 @16384 (16K, Q overlay), Vs @32768 (16K),
  //         Ps @49152 (8K, A overlay), Bs0 @57344 (5K), Bs1 @62464 (5K)
  __shared__ __align__(16) char lds[67584];
  char* const Vs = lds + 32768;
  char* const Ps = lds + 49152;

  const int tid = threadIdx.x;
  const int lane = tid & 63, w = tid >> 6;
  const int lr = lane & 15, g4 = lane >> 4;
  const int h  = blockIdx.x;
  const int by = blockIdx.y;
  const int qt = (by < 16) ? (31 - by) : (by - 16);   // balanced pairing
  const int q0 = qt * 64;
  const int kvh = h >> 2;
  const short* Kh = Kg + kvh * 128;
  const short* Vh = Vtg + (size_t)(kvh * 128) * 2048;

  float pol   = fminf(fmaxf(pol_dir[h], -1.f), 1.f);
  float gamma = fmaxf(log1pf(__expf(gtp_gamma[h])), 1e-6f);
  float gate  = (1.f / (1.f + __expf(-pol_gate[h]))) * LOG2E;
  const float c_h  = -(pol * (1.f / 4096.f) + gamma) * LOG2E;  // log2-domain
  const float c16  = 16.f * c_h;
  const float chr1 = c_h, chr2 = c_h + c_h, chr3 = chr2 + c_h;
  const float sc = 0.08838834764831845f * LOG2E;   // log2e/sqrt(128)
  const f32x4 z4 = {0.f, 0.f, 0.f, 0.f};

  // ---- prologue: K0/V0 via global_load_lds (pre-swizzled source) ----
  #pragma unroll
  for (int s = 0; s < 4; ++s) {
    int idx = (w * 4 + s) * 64 + lane;
    int row = idx >> 4, slot = idx & 15;
    gload_lds16(Kh + (size_t)row * 512 + (slot ^ (row & 7)) * 8,
                lds + (w * 4 + s) * 1024);
  }
  #pragma unroll
  for (int s = 0; s < 4; ++s) {
    int idx = (w * 4 + s) * 64 + lane;
    int row = idx >> 3, slot = idx & 7;
    gload_lds16(Vh + (size_t)row * 2048 + (slot ^ (row & 7)) * 8,
                Vs + (w * 4 + s) * 1024);
  }
  // Q -> Kb1 overlay (swizzled) WITH FUSED RoPE: job c handles row=c>>3,
  // slot-pair (sl, sl+8) = cols [sl*8, sl*8+8) and [+64).
  #pragma unroll
  for (int s = 0; s < 2; ++s) {
    int c = tid + s * 256;            // 0..511
    int row = c >> 3, sl = c & 7;
    const short* qrow = Qg + (size_t)(q0 + row) * 2048 + h * 128;
    int4 vlo = *(const int4*)(qrow + sl * 8);
    int4 vhi = *(const int4*)(qrow + 64 + sl * 8);
    short* lop = (short*)&vlo;
    short* hip = (short*)&vhi;
    short rlo[8], rhi[8];
    float tf = (float)(q0 + row);
    #pragma unroll
    for (int j = 0; j < 8; ++j) {
      int d = sl * 8 + j;
      float inv = __expf((float)d * -0.14391156831212789f);  // 10000^(-d/64)
      float ang = tf * inv;
      float sn, cs;
      __sincosf(ang, &sn, &cs);
      float x1 = bf2f(lop[j]), x2 = bf2f(hip[j]);
      rlo[j] = f2bf(x1 * cs - x2 * sn);
      rhi[j] = f2bf(x2 * cs + x1 * sn);
    }
    *(int4*)(lds + 16384 + row * 256 + ((sl * 16) ^ ((row & 7) << 4))) =
        *(int4*)rlo;
    *(int4*)(lds + 16384 + row * 256 + (((sl + 8) * 16) ^ ((row & 7) << 4))) =
        *(int4*)rhi;
  }
  {
    int row = tid >> 2, sl = tid & 3;
    int4 va = *(const int4*)(Ag + (size_t)(q0 + row) * 32 + sl * 8);
    *(int4*)(Ps + row * 80 + sl * 16) = va;
    int4 vb = *(const int4*)(Bg + (size_t)row * 32 + sl * 8);
    *(int4*)(lds + 57344 + row * 80 + sl * 16) = vb;
  }
  asm volatile("s_waitcnt vmcnt(0) lgkmcnt(0)" ::: "memory");
  __builtin_amdgcn_s_barrier();

  // hoist Q frags (q-row = w*16+lr) and A frag
  bf16x8 qf[4];
  #pragma unroll
  for (int kk = 0; kk < 4; ++kk)
    qf[kk] = *(const bf16x8*)(lds + 16384 + (w * 16 + lr) * 256 +
                              ((kk * 64 + g4 * 16) ^ ((lr & 7) << 4)));
  bf16x8 afr = *(const bf16x8*)(Ps + (w * 16 + lr) * 80 + g4 * 16);
  asm volatile("s_waitcnt lgkmcnt(0)" ::: "memory");
  __builtin_amdgcn_s_barrier();   // Kb1 + Ps now free for K-dbuf / P

  f32x4 acc_o[8];
  #pragma unroll
  for (int i = 0; i < 8; ++i) acc_o[i] = z4;
  float m_st = -INFINITY, l_st = 0.f;
  char* Pw = Ps + w * 2048;

  for (int jt = 0; jt <= qt; ++jt) {
    const int j0 = jt * 64;
    const bool pf = (jt < qt);
    char* Kcur = lds + ((jt & 1) << 14);
    char* Knxt = lds + (((jt + 1) & 1) << 14);
    char* Bcur = lds + 57344 + (jt & 1) * 5120;
    char* Bnxt = lds + 57344 + ((jt + 1) & 1) * 5120;

    // ---- issue next K tile (LDS dbuf, no VGPR cost) + B reg load ----
    int4 breg;
    if (pf) {
      int brow = tid >> 2, bsl = tid & 3;
      breg = *(const int4*)(Bg + (size_t)(j0 + 64 + brow) * 32 + bsl * 8);
      #pragma unroll
      for (int s = 0; s < 4; ++s) {
        int idx = (w * 4 + s) * 64 + lane;
        int row = idx >> 4, slot = idx & 15;
        gload_lds16(Kh + (size_t)(j0 + 64 + row) * 512 + (slot ^ (row & 7)) * 8,
                    Knxt + (w * 4 + s) * 1024);
      }
    }

    // ---- S^T = K.Q^T, md = Bm.A^T ----
    f32x4 acc_s[4], md4[4];
    __builtin_amdgcn_s_setprio(1);
    #pragma unroll
    for (int cb = 0; cb < 4; ++cb) {
      acc_s[cb] = z4;
      #pragma unroll
      for (int kk = 0; kk < 4; ++kk) {
        bf16x8 kf = *(const bf16x8*)(Kcur + (cb * 16 + lr) * 256 +
                                     ((kk * 64 + g4 * 16) ^ ((lr & 7) << 4)));
        acc_s[cb] = MFMA16(kf, qf[kk], acc_s[cb], 0, 0, 0);
      }
      bf16x8 bmf = *(const bf16x8*)(Bcur + (cb * 16 + lr) * 80 + g4 * 16);
      md4[cb] = MFMA16(bmf, afr, z4, 0, 0, 0);
    }
    __builtin_amdgcn_s_setprio(0);

    // ---- bias + (diag-only) mask, all in log2 domain ----
    const int dq = q0 + w * 16 + lr - j0;    // qi - j0
    float bq = c_h * (float)(dq - g4 * 4);
    #pragma unroll
    for (int cb = 0; cb < 4; ++cb) {
      float bcb = bq - c16 * (float)cb;
      float sig0 = rcpf(1.f + ex2(-md4[cb][0]));
      float sig1 = rcpf(1.f + ex2(-md4[cb][1]));
      float sig2 = rcpf(1.f + ex2(-md4[cb][2]));
      float sig3 = rcpf(1.f + ex2(-md4[cb][3]));
      acc_s[cb][0] = fmaf(acc_s[cb][0], sc, fmaf(gate, sig0, bcb));
      acc_s[cb][1] = fmaf(acc_s[cb][1], sc, fmaf(gate, sig1, bcb - chr1));
      acc_s[cb][2] = fmaf(acc_s[cb][2], sc, fmaf(gate, sig2, bcb - chr2));
      acc_s[cb][3] = fmaf(acc_s[cb][3], sc, fmaf(gate, sig3, bcb - chr3));
    }
    if (jt == qt) {   // causal mask needed only on the diagonal tile
      #pragma unroll
      for (int cb = 0; cb < 4; ++cb)
        #pragma unroll
        for (int r = 0; r < 4; ++r)
          if (cb * 16 + g4 * 4 + r > dq) acc_s[cb][r] = -INFINITY;
    }

    // ---- online softmax, defer-max (THR = 8*log2e) ----
    float t0 = fmaxf(fmaxf(acc_s[0][0], acc_s[0][1]), acc_s[0][2]);
    float t1 = fmaxf(fmaxf(acc_s[0][3], acc_s[1][0]), acc_s[1][1]);
    float t2 = fmaxf(fmaxf(acc_s[1][2], acc_s[1][3]), acc_s[2][0]);
    float t3 = fmaxf(fmaxf(acc_s[2][1], acc_s[2][2]), acc_s[2][3]);
    float t4 = fmaxf(fmaxf(acc_s[3][0], acc_s[3][1]), acc_s[3][2]);
    float mx = fmaxf(fmaxf(fmaxf(t0, t1), t2),
                     fmaxf(fmaxf(t3, t4), acc_s[3][3]));
    mx = fmaxf(mx, __shfl_xor(mx, 16));
    mx = fmaxf(mx, __shfl_xor(mx, 32));
    if (!__all(mx - m_st <= 11.5415603f)) {
      float mn = fmaxf(m_st, mx);
      float es = ex2(m_st - mn);   // first tile: exp2(-inf)=0
      l_st *= es;
      m_st = mn;
      float es4[4];
      #pragma unroll
      for (int r = 0; r < 4; ++r) es4[r] = __shfl(es, g4 * 4 + r, 64);
      #pragma unroll
      for (int db = 0; db < 8; ++db)
        #pragma unroll
        for (int r = 0; r < 4; ++r) acc_o[db][r] *= es4[r];
    }
    float rs = 0.f;
    #pragma unroll
    for (int cb = 0; cb < 4; ++cb)
      #pragma unroll
      for (int r = 0; r < 4; ++r) {
        float p = ex2(acc_s[cb][r] - m_st);
        acc_s[cb][r] = p;
        rs += p;
      }
    rs += __shfl_xor(rs, 16);
    rs += __shfl_xor(rs, 32);
    l_st += rs;

    // ---- P -> LDS (v_cvt_pk_bf16_f32); wait V landed (counted vmcnt) ----
    #pragma unroll
    for (int cb = 0; cb < 4; ++cb) {
      uint2 uu;
      uu.x = cvtpk(acc_s[cb][0], acc_s[cb][1]);
      uu.y = cvtpk(acc_s[cb][2], acc_s[cb][3]);
      *(uint2*)(Pw + lr * 128 + ((cb * 32 + g4 * 8) ^ ((lr & 7) << 4))) = uu;
    }
    asm volatile("s_waitcnt lgkmcnt(0)" ::: "memory");
    if (pf) asm volatile("s_waitcnt vmcnt(5)" ::: "memory");
    else    asm volatile("s_waitcnt vmcnt(0)" ::: "memory");
    __builtin_amdgcn_s_barrier();          // V visible to all waves
    __builtin_amdgcn_sched_barrier(0);

    // ---- PV ----
    __builtin_amdgcn_s_setprio(1);
    #pragma unroll
    for (int kk = 0; kk < 2; ++kk) {
      bf16x8 pfr = *(const bf16x8*)(Pw + lr * 128 +
                                    ((kk * 64 + g4 * 16) ^ ((lr & 7) << 4)));
      #pragma unroll
      for (int db = 0; db < 8; ++db) {
        bf16x8 vf = *(const bf16x8*)(Vs + (db * 16 + lr) * 128 +
                                     ((kk * 64 + g4 * 16) ^ ((lr & 7) << 4)));
        acc_o[db] = MFMA16(pfr, vf, acc_o[db], 0, 0, 0);
      }
    }
    __builtin_amdgcn_s_setprio(0);
    __builtin_amdgcn_sched_barrier(0);

    // ---- B dbuf write; drain K[jt+1]; end barrier; then stage V[jt+1] ----
    if (pf) {
      int brow = tid >> 2, bsl = tid & 3;
      *(int4*)(Bnxt + brow * 80 + bsl * 16) = breg;
    }
    asm volatile("s_waitcnt vmcnt(0) lgkmcnt(0)" ::: "memory");
    __builtin_amdgcn_s_barrier();
    if (pf) {
      #pragma unroll
      for (int s = 0; s < 4; ++s) {
        int idx = (w * 4 + s) * 64 + lane;
        int row = idx >> 3, slot = idx & 7;
        gload_lds16(Vh + (size_t)row * 2048 + (j0 + 64) + (slot ^ (row & 7)) * 8,
                    Vs + (w * 4 + s) * 1024);
      }
    }
  }

  // epilogue: normalize, store bf16 AO. acc rows q = g4*4+r, col d = db*16+lr.
  float lrcp[4];
  #pragma unroll
  for (int r = 0; r < 4; ++r) lrcp[r] = 1.f / __shfl(l_st, g4 * 4 + r, 64);
  #pragma unroll
  for (int db = 0; db < 8; ++db)
    #pragma unroll
    for (int r = 0; r < 4; ++r)
      AO[(size_t)(q0 + w * 16 + g4 * 4 + r) * 2048 + h * 128 + db * 16 + lr] =
          f2bf(acc_o[db][r] * lrcp[r]);
}

// ---------------------------------------------------------------------------
// Launch
// ---------------------------------------------------------------------------
extern "C" void kernel_launch(void* const* d_in, const int* in_sizes, int n_in,
                              void* d_out, int out_size, void* d_ws, size_t ws_size,
                              hipStream_t stream) {
  const float* x         = (const float*)d_in[0];
  const float* Wq        = (const float*)d_in[1];
  const float* Wk        = (const float*)d_in[2];
  const float* Wv        = (const float*)d_in[3];
  const float* Wo        = (const float*)d_in[4];
  const float* pol_dir   = (const float*)d_in[5];
  const float* pol_WA    = (const float*)d_in[6];
  const float* pol_WB    = (const float*)d_in[7];
  const float* pol_gate  = (const float*)d_in[8];
  const float* gtp_gamma = (const float*)d_in[9];
  float* out = (float*)d_out;

  char* ws = (char*)d_ws;
  short* Qb   = (short*)(ws);                    // 2048x2048 bf16 = 8 MB
  short* Kb   = (short*)(ws + 8388608);          // 2048x512  bf16 = 2 MB
  short* Vtb  = (short*)(ws + 10485760);         // 512x2048  bf16 = 2 MB (V^T)
  short* Ab   = (short*)(ws + 12582912);         // 2048x32   bf16 = 128 KB
  short* Bb   = (short*)(ws + 12713984);         // 2048x32   bf16 = 128 KB
  short* Wot  = (short*)(ws + 12845056);         // 8 MB
  short* Wqt  = (short*)(ws + 21233664);         // 8 MB (reused as AO after qkv)
  short* AO   = Wqt;                             // written by attn (Wqt dead)
  short* Wkt  = (short*)(ws + 29622272);         // 2 MB
  short* Wvt  = (short*)(ws + 31719424);         // 2 MB
  short* WABt = (short*)(ws + 33816576);         // 512 KB
  short* xb   = (short*)(ws + 34340864);         // 8 MB
  // total 42.7 MB

  prep_kernel<<<14464, 256, 0, stream>>>(x, Wq, Wk, Wv, pol_WA, pol_WB, Wo,
                                         xb, Wqt, Wkt, Wvt, WABt, Wot);
  gemm_qkv_kernel<<<784, 256, 0, stream>>>(xb, Wqt, Wkt, Wvt, WABt,
                                           Qb, Kb, Vtb, Ab, Bb);
  ropek_kernel<<<2048, 256, 0, stream>>>(Kb);
  attn_kernel<<<dim3(16, 32), 256, 0, stream>>>(Qb, Kb, Vtb, Ab, Bb,
                                                pol_dir, pol_gate, gtp_gamma, AO);
  gemm_out_kernel<<<512, 256, 0, stream>>>(AO, Wot, out);
}

// Round 16
// 150.202 us; speedup vs baseline: 1.0434x; 1.0023x over previous
//
#include <hip/hip_runtime.h>
#include <math.h>

// ---------------------------------------------------------------------------
// Types / helpers
// ---------------------------------------------------------------------------
typedef short bf16x8 __attribute__((ext_vector_type(8)));   // 8 bf16 (4 VGPRs)
typedef float f32x4  __attribute__((ext_vector_type(4)));

#define MFMA16 __builtin_amdgcn_mfma_f32_16x16x32_bf16
#define LOG2E 1.4426950408889634f

static __device__ __forceinline__ short f2bf(float f) {
  union { float f; unsigned u; } x; x.f = f;
  unsigned r = (x.u + 0x7FFFu + ((x.u >> 16) & 1u)) >> 16;  // RTNE
  return (short)r;
}
static __device__ __forceinline__ unsigned packbf(float a, float b) {
  return (unsigned)(unsigned short)f2bf(a) | ((unsigned)(unsigned short)f2bf(b) << 16);
}
static __device__ __forceinline__ float bf2f(short s) {
  union { unsigned u; float f; } x; x.u = ((unsigned)(unsigned short)s) << 16;
  return x.f;
}
static __device__ __forceinline__ void gload_lds16(const void* g, void* l) {
  __builtin_amdgcn_global_load_lds((const __attribute__((address_space(1))) void*)g,
                                   (__attribute__((address_space(3))) void*)l, 16, 0, 0);
}
static __device__ __forceinline__ float ex2(float x) {
  float r; asm("v_exp_f32 %0, %1" : "=v"(r) : "v"(x)); return r;
}
static __device__ __forceinline__ float rcpf(float x) {
  float r; asm("v_rcp_f32 %0, %1" : "=v"(r) : "v"(x)); return r;
}
static __device__ __forceinline__ unsigned cvtpk(float lo, float hi) {
  unsigned r; asm("v_cvt_pk_bf16_f32 %0, %1, %2" : "=v"(r) : "v"(lo), "v"(hi));
  return r;
}

// ---------------------------------------------------------------------------
// Transpose one 32x32 tile: fp32 in [K][N] -> bf16 out [N][K]
// ---------------------------------------------------------------------------
__device__ __forceinline__ void tr_tile(
    const float* __restrict__ in, short* __restrict__ out,
    int K, int N, int nt, int kt, float (*t)[33])
{
  int n0 = nt * 32, k0 = kt * 32;
  int tx = threadIdx.x & 31, ty = threadIdx.x >> 5;
  #pragma unroll
  for (int i = 0; i < 4; ++i)
    t[ty + 8 * i][tx] = in[(size_t)(k0 + ty + 8 * i) * N + n0 + tx];
  __syncthreads();
  #pragma unroll
  for (int i = 0; i < 4; ++i)
    out[(size_t)(n0 + ty + 8 * i) * K + k0 + tx] = f2bf(t[tx][ty + 8 * i]);
}

// Fused prep: Wq/Wk/Wv/WA/WB/Wo transposes + x fp32->bf16 convert. grid 14464.
__global__ __launch_bounds__(256) void prep_kernel(
    const float* __restrict__ x, const float* __restrict__ Wq,
    const float* __restrict__ Wk, const float* __restrict__ Wv,
    const float* __restrict__ WA, const float* __restrict__ WB,
    const float* __restrict__ Wo,
    short* __restrict__ xb, short* __restrict__ Wqt, short* __restrict__ Wkt,
    short* __restrict__ Wvt, short* __restrict__ WABt, short* __restrict__ Wot)
{
  __shared__ float t[32][33];
  int b = blockIdx.x;
  if (b < 4096)       tr_tile(Wq, Wqt, 2048, 2048, b & 63, b >> 6, t);
  else if (b < 5120)  { int c = b - 4096; tr_tile(Wk, Wkt, 2048, 512, c & 15, c >> 4, t); }
  else if (b < 6144)  { int c = b - 5120; tr_tile(Wv, Wvt, 2048, 512, c & 15, c >> 4, t); }
  else if (b < 6208)  { int c = b - 6144; tr_tile(WA, WABt, 2048, 32, 0, c, t); }
  else if (b < 6272)  { int c = b - 6208; tr_tile(WB, WABt + 32 * 2048, 2048, 32, 0, c, t); }
  else if (b < 10368) {
    int i = (b - 6272) * 256 + threadIdx.x;          // 4096 blocks, 1M float4
    float4 v = ((const float4*)x)[i];
    short4 o; o.x = f2bf(v.x); o.y = f2bf(v.y); o.z = f2bf(v.z); o.w = f2bf(v.w);
    ((short4*)xb)[i] = o;
  } else {
    int c = b - 10368;                               // 4096 blocks
    tr_tile(Wo, Wot, 2048, 2048, c & 63, c >> 6, t);
  }
}

// RoPE on K only [2048][512] (4 heads, pairs (d, d+64)). grid 2048.
__global__ __launch_bounds__(256) void ropek_kernel(short* __restrict__ K)
{
  int idx = blockIdx.x * 256 + threadIdx.x;   // < 2048*4*64
  int d  = idx & 63;
  int hh = (idx >> 6) & 3;
  int tt = idx >> 8;
  short* base = K + (size_t)tt * 512 + hh * 128 + d;
  float inv = __expf((float)d * -0.14391156831212789f);  // 10000^(-d/64)
  float ang = (float)tt * inv;
  float sn, cs;
  __sincosf(ang, &sn, &cs);
  float x1 = bf2f(base[0]), x2 = bf2f(base[64]);
  base[0]  = f2bf(x1 * cs - x2 * sn);
  base[64] = f2bf(x2 * cs + x1 * sn);
}

// ---------------------------------------------------------------------------
// bf16 MFMA GEMM core, C 128(M)x64(N) tile, BK=64, single-buffer LDS with
// full __syncthreads drains. Pre-swizzled-source idiom for the 128B-row
// bank conflict. (measured good r10-r15)
// ---------------------------------------------------------------------------
__device__ __forceinline__ void gemm12864_core(
    const short* __restrict__ A, const short* __restrict__ Bt,
    int m0, int n0, int Kd, short* Asm /*128x64*/, short* Bsm /*64x64*/,
    f32x4 acc[4][2])
{
  const int tid = threadIdx.x;
  const int lane = tid & 63, w = tid >> 6;
  const int lr = lane & 15, g4 = lane >> 4;
  const int wm = w >> 1, wn = w & 1;

  for (int k0 = 0; k0 < Kd; k0 += 64) {
    #pragma unroll
    for (int s = 0; s < 4; ++s) {
      int c = (s * 4 + w) * 64 + lane;          // 0..1023
      int row = c >> 3, q = c & 7;
      gload_lds16(A + (size_t)(m0 + row) * Kd + k0 + (q ^ (row & 7)) * 8,
                  Asm + c * 8);
    }
    #pragma unroll
    for (int s = 0; s < 2; ++s) {
      int c = (s * 4 + w) * 64 + lane;          // 0..511
      int row = c >> 3, q = c & 7;
      gload_lds16(Bt + (size_t)(n0 + row) * Kd + k0 + (q ^ (row & 7)) * 8,
                  Bsm + c * 8);
    }
    __syncthreads();
    #pragma unroll
    for (int kk = 0; kk < 2; ++kk) {
      bf16x8 af[4], bff[2];
      #pragma unroll
      for (int mi = 0; mi < 4; ++mi) {
        int row = wm * 64 + mi * 16 + lr;       // row&7 == lr&7
        af[mi] = *(const bf16x8*)(Asm + row * 64 +
                                  ((kk * 4 + g4) ^ (lr & 7)) * 8);
      }
      #pragma unroll
      for (int ni = 0; ni < 2; ++ni) {
        int row = wn * 32 + ni * 16 + lr;
        bff[ni] = *(const bf16x8*)(Bsm + row * 64 +
                                   ((kk * 4 + g4) ^ (lr & 7)) * 8);
      }
      #pragma unroll
      for (int mi = 0; mi < 4; ++mi)
        #pragma unroll
        for (int ni = 0; ni < 2; ++ni)
          acc[mi][ni] = MFMA16(af[mi], bff[ni], acc[mi][ni], 0, 0, 0);
    }
    __syncthreads();
  }
}

// Fused QKV + low-rank AB projection. grid 784 (1D, XCD-swizzled: 784=8x98).
// V (mode 2) epilogue stages the 64x128 V^T tile through LDS so the HBM
// write is row-major coalesced (direct column-major write was ~8x
// write-allocate over-traffic).
__global__ __launch_bounds__(256, 3) void gemm_qkv_kernel(
    const short* __restrict__ xb, const short* __restrict__ Wqt,
    const short* __restrict__ Wkt, const short* __restrict__ Wvt,
    const short* __restrict__ WABt,
    short* __restrict__ Qb, short* __restrict__ Kb, short* __restrict__ Vtb,
    short* __restrict__ Ab, short* __restrict__ Bb)
{
  __shared__ __align__(16) short smem[128 * 64 + 64 * 64];  // Asm | Bsm
  short* const Asm = smem;
  short* const Bsm = smem + 128 * 64;
  f32x4 acc[4][2];
  #pragma unroll
  for (int i = 0; i < 4; ++i)
    #pragma unroll
    for (int j = 0; j < 2; ++j) acc[i][j] = (f32x4){0.f, 0.f, 0.f, 0.f};

  const int bid = (int)blockIdx.x;                 // 0..783
  const int swz = (bid & 7) * 98 + (bid >> 3);
  const int bx = swz % 49, by = swz / 49;

  const short* Bt; int mode, nl0;
  if (bx < 32)      { Bt = Wqt;  nl0 = bx * 64;        mode = 0; }
  else if (bx < 40) { Bt = Wkt;  nl0 = (bx - 32) * 64; mode = 1; }
  else if (bx < 48) { Bt = Wvt;  nl0 = (bx - 40) * 64; mode = 2; }
  else              { Bt = WABt; nl0 = 0;              mode = 3; }

  gemm12864_core(xb, Bt, by * 128, nl0, 2048, Asm, Bsm, acc);
  // core ends with __syncthreads -> smem reusable

  const int tid = threadIdx.x, lane = tid & 63, w = tid >> 6;
  const int lr = lane & 15, g4 = lane >> 4, wm = w >> 1, wn = w & 1;

  if (mode == 2) {
    // stage V^T tile [64 d-rows][128 t-cols] in LDS, pitch 132 shorts
    // (2-way bank aliasing only), then coalesced row-major global write.
    #pragma unroll
    for (int mi = 0; mi < 4; ++mi)
      #pragma unroll
      for (int ni = 0; ni < 2; ++ni) {
        int ml  = wm * 64 + mi * 16 + g4 * 4;       // t within tile
        int ncl = wn * 32 + ni * 16 + lr;           // d within tile
        #pragma unroll
        for (int r = 0; r < 4; ++r)
          smem[ncl * 132 + ml + r] = f2bf(acc[mi][ni][r]);
      }
    __syncthreads();
    {
      int row = tid >> 2, chunk = tid & 3;          // d-row, 32-short chunk
      const short* src = smem + row * 132 + chunk * 32;
      short* dst = Vtb + (size_t)(nl0 + row) * 2048 + by * 128 + chunk * 32;
      #pragma unroll
      for (int i = 0; i < 4; ++i)
        *(int4*)(dst + i * 8) = *(const int4*)(src + i * 8);
    }
    return;
  }

  #pragma unroll
  for (int mi = 0; mi < 4; ++mi) {
    #pragma unroll
    for (int ni = 0; ni < 2; ++ni) {
      int mb = by * 128 + wm * 64 + mi * 16 + g4 * 4;
      int ncl = wn * 32 + ni * 16 + lr;    // 0..63 within tile
      int nc = nl0 + ncl;
      if (mode == 0) {
        #pragma unroll
        for (int r = 0; r < 4; ++r)
          Qb[(size_t)(mb + r) * 2048 + nc] = f2bf(acc[mi][ni][r]);
      } else if (mode == 1) {
        #pragma unroll
        for (int r = 0; r < 4; ++r)
          Kb[(size_t)(mb + r) * 512 + nc] = f2bf(acc[mi][ni][r]);
      } else {
        #pragma unroll
        for (int r = 0; r < 4; ++r) {
          float sv = acc[mi][ni][r];
          if (ncl < 32) Ab[(size_t)(mb + r) * 32 + ncl] = f2bf(sv * LOG2E);
          else          Bb[(size_t)(mb + r) * 32 + (ncl - 32)] = f2bf(sv);
        }
      }
    }
  }
}

// Output projection: out = AO(bf16) @ Wo -> fp32. grid 512 (1D, 512=8x64).
__global__ __launch_bounds__(256, 3) void gemm_out_kernel(
    const short* __restrict__ AO, const short* __restrict__ Wot,
    float* __restrict__ out)
{
  __shared__ __align__(16) short Asm[128 * 64];
  __shared__ __align__(16) short Bsm[64 * 64];
  f32x4 acc[4][2];
  #pragma unroll
  for (int i = 0; i < 4; ++i)
    #pragma unroll
    for (int j = 0; j < 2; ++j) acc[i][j] = (f32x4){0.f, 0.f, 0.f, 0.f};

  const int bid = (int)blockIdx.x;                 // 0..511
  const int swz = (bid & 7) * 64 + (bid >> 3);
  const int bx = swz % 32, by = swz / 32;

  gemm12864_core(AO, Wot, by * 128, bx * 64, 2048, Asm, Bsm, acc);

  const int tid = threadIdx.x, lane = tid & 63, w = tid >> 6;
  const int lr = lane & 15, g4 = lane >> 4, wm = w >> 1, wn = w & 1;
  #pragma unroll
  for (int mi = 0; mi < 4; ++mi)
    #pragma unroll
    for (int ni = 0; ni < 2; ++ni) {
      int mb = by * 128 + wm * 64 + mi * 16 + g4 * 4;
      int nc = bx * 64 + wn * 32 + ni * 16 + lr;
      #pragma unroll
      for (int r = 0; r < 4; ++r)
        out[(size_t)(mb + r) * 2048 + nc] = acc[mi][ni][r];
    }
}

// ---------------------------------------------------------------------------
// Flash attention — r6 structure (measured 74.6us x3) with Q-RoPE fused into
// the Q-staging prologue. bf16 MFMA, exp2-domain softmax.
// grid (16 heads, 32 y), qt = (y<16) ? 31-y : y-16 (balanced pairing).
// LDS-double-buffered K (global_load_lds, pre-swizzled source), single V
// staged after the end barrier (counted vmcnt before PV). LDS 66KB.
// FROZEN from r12/r15 (measured best).
// ---------------------------------------------------------------------------
__global__ __launch_bounds__(256, 2) void attn_kernel(
    const short* __restrict__ Qg, const short* __restrict__ Kg,
    const short* __restrict__ Vtg, const short* __restrict__ Ag,
    const short* __restrict__ Bg, const float* __restrict__ pol_dir,
    const float* __restrict__ pol_gate, const float* __restrict__ gtp_gamma,
    short* __restrict__ AO)
{
  // layout: Kb0 @0 (16K), Kb1 @16384 (16K, Q overlay), Vs @32768 (16K),
  //         Ps @49152 (8K, A overlay), Bs0 @57344 (5K), Bs1 @62464 (5K)
  __shared__ __align__(16) char lds[67584];
  char* const Vs = lds + 32768;
  char* const Ps = lds + 49152;

  const int tid = threadIdx.x;
  const int lane = tid & 63, w = tid >> 6;
  const int lr = lane & 15, g4 = lane >> 4;
  const int h  = blockIdx.x;
  const int by = blockIdx.y;
  const int qt = (by < 16) ? (31 - by) : (by - 16);   // balanced pairing
  const int q0 = qt * 64;
  const int kvh = h >> 2;
  const short* Kh = Kg + kvh * 128;
  const short* Vh = Vtg + (size_t)(kvh * 128) * 2048;

  float pol   = fminf(fmaxf(pol_dir[h], -1.f), 1.f);
  float gamma = fmaxf(log1pf(__expf(gtp_gamma[h])), 1e-6f);
  float gate  = (1.f / (1.f + __expf(-pol_gate[h]))) * LOG2E;
  const float c_h  = -(pol * (1.f / 4096.f) + gamma) * LOG2E;  // log2-domain
  const float c16  = 16.f * c_h;
  const float chr1 = c_h, chr2 = c_h + c_h, chr3 = chr2 + c_h;
  const float sc = 0.08838834764831845f * LOG2E;   // log2e/sqrt(128)
  const f32x4 z4 = {0.f, 0.f, 0.f, 0.f};

  // ---- prologue: K0/V0 via global_load_lds (pre-swizzled source) ----
  #pragma unroll
  for (int s = 0; s < 4; ++s) {
    int idx = (w * 4 + s) * 64 + lane;
    int row = idx >> 4, slot = idx & 15;
    gload_lds16(Kh + (size_t)row * 512 + (slot ^ (row & 7)) * 8,
                lds + (w * 4 + s) * 1024);
  }
  #pragma unroll
  for (int s = 0; s < 4; ++s) {
    int idx = (w * 4 + s) * 64 + lane;
    int row = idx >> 3, slot = idx & 7;
    gload_lds16(Vh + (size_t)row * 2048 + (slot ^ (row & 7)) * 8,
                Vs + (w * 4 + s) * 1024);
  }
  // Q -> Kb1 overlay (swizzled) WITH FUSED RoPE: job c handles row=c>>3,
  // slot-pair (sl, sl+8) = cols [sl*8, sl*8+8) and [+64).
  #pragma unroll
  for (int s = 0; s < 2; ++s) {
    int c = tid + s * 256;            // 0..511
    int row = c >> 3, sl = c & 7;
    const short* qrow = Qg + (size_t)(q0 + row) * 2048 + h * 128;
    int4 vlo = *(const int4*)(qrow + sl * 8);
    int4 vhi = *(const int4*)(qrow + 64 + sl * 8);
    short* lop = (short*)&vlo;
    short* hip = (short*)&vhi;
    short rlo[8], rhi[8];
    float tf = (float)(q0 + row);
    #pragma unroll
    for (int j = 0; j < 8; ++j) {
      int d = sl * 8 + j;
      float inv = __expf((float)d * -0.14391156831212789f);  // 10000^(-d/64)
      float ang = tf * inv;
      float sn, cs;
      __sincosf(ang, &sn, &cs);
      float x1 = bf2f(lop[j]), x2 = bf2f(hip[j]);
      rlo[j] = f2bf(x1 * cs - x2 * sn);
      rhi[j] = f2bf(x2 * cs + x1 * sn);
    }
    *(int4*)(lds + 16384 + row * 256 + ((sl * 16) ^ ((row & 7) << 4))) =
        *(int4*)rlo;
    *(int4*)(lds + 16384 + row * 256 + (((sl + 8) * 16) ^ ((row & 7) << 4))) =
        *(int4*)rhi;
  }
  {
    int row = tid >> 2, sl = tid & 3;
    int4 va = *(const int4*)(Ag + (size_t)(q0 + row) * 32 + sl * 8);
    *(int4*)(Ps + row * 80 + sl * 16) = va;
    int4 vb = *(const int4*)(Bg + (size_t)row * 32 + sl * 8);
    *(int4*)(lds + 57344 + row * 80 + sl * 16) = vb;
  }
  asm volatile("s_waitcnt vmcnt(0) lgkmcnt(0)" ::: "memory");
  __builtin_amdgcn_s_barrier();

  // hoist Q frags (q-row = w*16+lr) and A frag
  bf16x8 qf[4];
  #pragma unroll
  for (int kk = 0; kk < 4; ++kk)
    qf[kk] = *(const bf16x8*)(lds + 16384 + (w * 16 + lr) * 256 +
                              ((kk * 64 + g4 * 16) ^ ((lr & 7) << 4)));
  bf16x8 afr = *(const bf16x8*)(Ps + (w * 16 + lr) * 80 + g4 * 16);
  asm volatile("s_waitcnt lgkmcnt(0)" ::: "memory");
  __builtin_amdgcn_s_barrier();   // Kb1 + Ps now free for K-dbuf / P

  f32x4 acc_o[8];
  #pragma unroll
  for (int i = 0; i < 8; ++i) acc_o[i] = z4;
  float m_st = -INFINITY, l_st = 0.f;
  char* Pw = Ps + w * 2048;

  for (int jt = 0; jt <= qt; ++jt) {
    const int j0 = jt * 64;
    const bool pf = (jt < qt);
    char* Kcur = lds + ((jt & 1) << 14);
    char* Knxt = lds + (((jt + 1) & 1) << 14);
    char* Bcur = lds + 57344 + (jt & 1) * 5120;
    char* Bnxt = lds + 57344 + ((jt + 1) & 1) * 5120;

    // ---- issue next K tile (LDS dbuf, no VGPR cost) + B reg load ----
    int4 breg;
    if (pf) {
      int brow = tid >> 2, bsl = tid & 3;
      breg = *(const int4*)(Bg + (size_t)(j0 + 64 + brow) * 32 + bsl * 8);
      #pragma unroll
      for (int s = 0; s < 4; ++s) {
        int idx = (w * 4 + s) * 64 + lane;
        int row = idx >> 4, slot = idx & 15;
        gload_lds16(Kh + (size_t)(j0 + 64 + row) * 512 + (slot ^ (row & 7)) * 8,
                    Knxt + (w * 4 + s) * 1024);
      }
    }

    // ---- S^T = K.Q^T, md = Bm.A^T ----
    f32x4 acc_s[4], md4[4];
    __builtin_amdgcn_s_setprio(1);
    #pragma unroll
    for (int cb = 0; cb < 4; ++cb) {
      acc_s[cb] = z4;
      #pragma unroll
      for (int kk = 0; kk < 4; ++kk) {
        bf16x8 kf = *(const bf16x8*)(Kcur + (cb * 16 + lr) * 256 +
                                     ((kk * 64 + g4 * 16) ^ ((lr & 7) << 4)));
        acc_s[cb] = MFMA16(kf, qf[kk], acc_s[cb], 0, 0, 0);
      }
      bf16x8 bmf = *(const bf16x8*)(Bcur + (cb * 16 + lr) * 80 + g4 * 16);
      md4[cb] = MFMA16(bmf, afr, z4, 0, 0, 0);
    }
    __builtin_amdgcn_s_setprio(0);

    // ---- bias + (diag-only) mask, all in log2 domain ----
    const int dq = q0 + w * 16 + lr - j0;    // qi - j0
    float bq = c_h * (float)(dq - g4 * 4);
    #pragma unroll
    for (int cb = 0; cb < 4; ++cb) {
      float bcb = bq - c16 * (float)cb;
      float sig0 = rcpf(1.f + ex2(-md4[cb][0]));
      float sig1 = rcpf(1.f + ex2(-md4[cb][1]));
      float sig2 = rcpf(1.f + ex2(-md4[cb][2]));
      float sig3 = rcpf(1.f + ex2(-md4[cb][3]));
      acc_s[cb][0] = fmaf(acc_s[cb][0], sc, fmaf(gate, sig0, bcb));
      acc_s[cb][1] = fmaf(acc_s[cb][1], sc, fmaf(gate, sig1, bcb - chr1));
      acc_s[cb][2] = fmaf(acc_s[cb][2], sc, fmaf(gate, sig2, bcb - chr2));
      acc_s[cb][3] = fmaf(acc_s[cb][3], sc, fmaf(gate, sig3, bcb - chr3));
    }
    if (jt == qt) {   // causal mask needed only on the diagonal tile
      #pragma unroll
      for (int cb = 0; cb < 4; ++cb)
        #pragma unroll
        for (int r = 0; r < 4; ++r)
          if (cb * 16 + g4 * 4 + r > dq) acc_s[cb][r] = -INFINITY;
    }

    // ---- online softmax, defer-max (THR = 8*log2e) ----
    float t0 = fmaxf(fmaxf(acc_s[0][0], acc_s[0][1]), acc_s[0][2]);
    float t1 = fmaxf(fmaxf(acc_s[0][3], acc_s[1][0]), acc_s[1][1]);
    float t2 = fmaxf(fmaxf(acc_s[1][2], acc_s[1][3]), acc_s[2][0]);
    float t3 = fmaxf(fmaxf(acc_s[2][1], acc_s[2][2]), acc_s[2][3]);
    float t4 = fmaxf(fmaxf(acc_s[3][0], acc_s[3][1]), acc_s[3][2]);
    float mx = fmaxf(fmaxf(fmaxf(t0, t1), t2),
                     fmaxf(fmaxf(t3, t4), acc_s[3][3]));
    mx = fmaxf(mx, __shfl_xor(mx, 16));
    mx = fmaxf(mx, __shfl_xor(mx, 32));
    if (!__all(mx - m_st <= 11.5415603f)) {
      float mn = fmaxf(m_st, mx);
      float es = ex2(m_st - mn);   // first tile: exp2(-inf)=0
      l_st *= es;
      m_st = mn;
      float es4[4];
      #pragma unroll
      for (int r = 0; r < 4; ++r) es4[r] = __shfl(es, g4 * 4 + r, 64);
      #pragma unroll
      for (int db = 0; db < 8; ++db)
        #pragma unroll
        for (int r = 0; r < 4; ++r) acc_o[db][r] *= es4[r];
    }
    float rs = 0.f;
    #pragma unroll
    for (int cb = 0; cb < 4; ++cb)
      #pragma unroll
      for (int r = 0; r < 4; ++r) {
        float p = ex2(acc_s[cb][r] - m_st);
        acc_s[cb][r] = p;
        rs += p;
      }
    rs += __shfl_xor(rs, 16);
    rs += __shfl_xor(rs, 32);
    l_st += rs;

    // ---- P -> LDS (v_cvt_pk_bf16_f32); wait V landed (counted vmcnt) ----
    #pragma unroll
    for (int cb = 0; cb < 4; ++cb) {
      uint2 uu;
      uu.x = cvtpk(acc_s[cb][0], acc_s[cb][1]);
      uu.y = cvtpk(acc_s[cb][2], acc_s[cb][3]);
      *(uint2*)(Pw + lr * 128 + ((cb * 32 + g4 * 8) ^ ((lr & 7) << 4))) = uu;
    }
    asm volatile("s_waitcnt lgkmcnt(0)" ::: "memory");
    if (pf) asm volatile("s_waitcnt vmcnt(5)" ::: "memory");
    else    asm volatile("s_waitcnt vmcnt(0)" ::: "memory");
    __builtin_amdgcn_s_barrier();          // V visible to all waves
    __builtin_amdgcn_sched_barrier(0);

    // ---- PV ----
    __builtin_amdgcn_s_setprio(1);
    #pragma unroll
    for (int kk = 0; kk < 2; ++kk) {
      bf16x8 pfr = *(const bf16x8*)(Pw + lr * 128 +
                                    ((kk * 64 + g4 * 16) ^ ((lr & 7) << 4)));
      #pragma unroll
      for (int db = 0; db < 8; ++db) {
        bf16x8 vf = *(const bf16x8*)(Vs + (db * 16 + lr) * 128 +
                                     ((kk * 64 + g4 * 16) ^ ((lr & 7) << 4)));
        acc_o[db] = MFMA16(pfr, vf, acc_o[db], 0, 0, 0);
      }
    }
    __builtin_amdgcn_s_setprio(0);
    __builtin_amdgcn_sched_barrier(0);

    // ---- B dbuf write; drain K[jt+1]; end barrier; then stage V[jt+1] ----
    if (pf) {
      int brow = tid >> 2, bsl = tid & 3;
      *(int4*)(Bnxt + brow * 80 + bsl * 16) = breg;
    }
    asm volatile("s_waitcnt vmcnt(0) lgkmcnt(0)" ::: "memory");
    __builtin_amdgcn_s_barrier();
    if (pf) {
      #pragma unroll
      for (int s = 0; s < 4; ++s) {
        int idx = (w * 4 + s) * 64 + lane;
        int row = idx >> 3, slot = idx & 7;
        gload_lds16(Vh + (size_t)row * 2048 + (j0 + 64) + (slot ^ (row & 7)) * 8,
                    Vs + (w * 4 + s) * 1024);
      }
    }
  }

  // epilogue: normalize, store bf16 AO. acc rows q = g4*4+r, col d = db*16+lr.
  float lrcp[4];
  #pragma unroll
  for (int r = 0; r < 4; ++r) lrcp[r] = 1.f / __shfl(l_st, g4 * 4 + r, 64);
  #pragma unroll
  for (int db = 0; db < 8; ++db)
    #pragma unroll
    for (int r = 0; r < 4; ++r)
      AO[(size_t)(q0 + w * 16 + g4 * 4 + r) * 2048 + h * 128 + db * 16 + lr] =
          f2bf(acc_o[db][r] * lrcp[r]);
}

// ---------------------------------------------------------------------------
// Launch
// ---------------------------------------------------------------------------
extern "C" void kernel_launch(void* const* d_in, const int* in_sizes, int n_in,
                              void* d_out, int out_size, void* d_ws, size_t ws_size,
                              hipStream_t stream) {
  const float* x         = (const float*)d_in[0];
  const float* Wq        = (const float*)d_in[1];
  const float* Wk        = (const float*)d_in[2];
  const float* Wv        = (const float*)d_in[3];
  const float* Wo        = (const float*)d_in[4];
  const float* pol_dir   = (const float*)d_in[5];
  const float* pol_WA    = (const float*)d_in[6];
  const float* pol_WB    = (const float*)d_in[7];
  const float* pol_gate  = (const float*)d_in[8];
  const float* gtp_gamma = (const float*)d_in[9];
  float* out = (float*)d_out;

  char* ws = (char*)d_ws;
  short* Qb   = (short*)(ws);                    // 2048x2048 bf16 = 8 MB
  short* Kb   = (short*)(ws + 8388608);          // 2048x512  bf16 = 2 MB
  short* Vtb  = (short*)(ws + 10485760);         // 512x2048  bf16 = 2 MB (V^T)
  short* Ab   = (short*)(ws + 12582912);         // 2048x32   bf16 = 128 KB
  short* Bb   = (short*)(ws + 12713984);         // 2048x32   bf16 = 128 KB
  short* Wot  = (short*)(ws + 12845056);         // 8 MB
  short* Wqt  = (short*)(ws + 21233664);         // 8 MB (reused as AO after qkv)
  short* AO   = Wqt;                             // written by attn (Wqt dead)
  short* Wkt  = (short*)(ws + 29622272);         // 2 MB
  short* Wvt  = (short*)(ws + 31719424);         // 2 MB
  short* WABt = (short*)(ws + 33816576);         // 512 KB
  short* xb   = (short*)(ws + 34340864);         // 8 MB
  // total 42.7 MB

  prep_kernel<<<14464, 256, 0, stream>>>(x, Wq, Wk, Wv, pol_WA, pol_WB, Wo,
                                         xb, Wqt, Wkt, Wvt, WABt, Wot);
  gemm_qkv_kernel<<<784, 256, 0, stream>>>(xb, Wqt, Wkt, Wvt, WABt,
                                           Qb, Kb, Vtb, Ab, Bb);
  ropek_kernel<<<2048, 256, 0, stream>>>(Kb);
  attn_kernel<<<dim3(16, 32), 256, 0, stream>>>(Qb, Kb, Vtb, Ab, Bb,
                                                pol_dir, pol_gate, gtp_gamma, AO);
  gemm_out_kernel<<<512, 256, 0, stream>>>(AO, Wot, out);
}